// Round 1
// baseline (343.547 us; speedup 1.0000x reference)
//
#include <hip/hip_runtime.h>

#define BATCH 65536
#define TB 64
#define AST 168   // A-tile LDS row stride (halves): 336B -> bank-conflict free b128 reads
#define HST 264   // H-tile LDS row stride (halves): 528B -> bank-conflict free b128 reads

typedef _Float16 half8 __attribute__((ext_vector_type(8)));
typedef float fx4 __attribute__((ext_vector_type(4)));

// workspace layout (in halves)
#define PW1_OFF 0        // [5][256][32]  phi_w1, K padded 146->160
#define PW2_OFF 40960    // [8][256][32]  phi_w2
#define PWR_OFF 106496   // [8][256][32]  rho_w1
#define PWH_OFF 172032   // [8][16][32]   [mean_w | lstd_w | zero-pad] N padded 8->16
#define WS_TOTAL 176128

__global__ __launch_bounds__(256) void prep_weights(
    const float* __restrict__ w1, const float* __restrict__ w2,
    const float* __restrict__ wr, const float* __restrict__ wm,
    const float* __restrict__ wl, _Float16* __restrict__ ws)
{
  int idx = blockIdx.x * 256 + threadIdx.x;
  if (idx < 40960) {
    int kk = idx & 31, n = (idx >> 5) & 255, kt = idx >> 13;
    int k = kt * 32 + kk;
    ws[idx] = (k < 146) ? (_Float16)w1[k * 256 + n] : (_Float16)0.f;
  } else if (idx < 106496) {
    int t = idx - 40960;
    int kk = t & 31, n = (t >> 5) & 255, kt = t >> 13;
    ws[idx] = (_Float16)w2[(kt * 32 + kk) * 256 + n];
  } else if (idx < 172032) {
    int t = idx - 106496;
    int kk = t & 31, n = (t >> 5) & 255, kt = t >> 13;
    ws[idx] = (_Float16)wr[(kt * 32 + kk) * 256 + n];
  } else if (idx < WS_TOTAL) {
    int t = idx - 172032;
    int kk = t & 31, n = (t >> 5) & 15, kt = t >> 9;
    int k = kt * 32 + kk;
    _Float16 v = (_Float16)0.f;
    if (n < 4) v = (_Float16)wm[k * 4 + n];
    else if (n < 8) v = (_Float16)wl[k * 4 + (n - 4)];
    ws[PWH_OFF + t] = v;
  }
}

__global__ __launch_bounds__(256, 2) void actor_fused(
    const float* __restrict__ obs, const float* __restrict__ lemb,
    const _Float16* __restrict__ ws,
    const float* __restrict__ b1, const float* __restrict__ b2,
    const float* __restrict__ br, const float* __restrict__ bm,
    const float* __restrict__ bl, float* __restrict__ out)
{
  __shared__ __align__(16) _Float16 As[TB * AST]; // input rows, K=160 used + pad
  __shared__ __align__(16) _Float16 Hs[TB * HST]; // h1 / agg / r staging (64x256)
  __shared__ _Float16 Fs[TB * 45];                // per-row object features

  const _Float16* __restrict__ pw1 = ws + PW1_OFF;
  const _Float16* __restrict__ pw2 = ws + PW2_OFF;
  const _Float16* __restrict__ pwr = ws + PWR_OFF;
  const _Float16* __restrict__ pwh = ws + PWH_OFF;

  const int tid = threadIdx.x;
  const int wave = tid >> 6;
  const int lane = tid & 63;
  const int q = lane >> 4;      // quad 0..3
  const int l16 = lane & 15;
  const int colbase = wave * 64; // this wave owns output cols [colbase, colbase+64)
  const int rowbase = blockIdx.x * TB;

  // ---- init: stage l_emb into A cols 0..99 ----
  for (int idx = tid; idx < TB * 100; idx += 256) {
    int r = idx / 100, c = idx - r * 100;
    As[r * AST + c] = (_Float16)lemb[(rowbase + r) * 100 + c];
  }
  // obs: body -> A cols 100..109, object feats -> Fs
  for (int idx = tid; idx < TB * 55; idx += 256) {
    int r = idx / 55, c = idx - r * 55;
    float v = obs[(rowbase + r) * 55 + c];
    if (c < 10) As[r * AST + 100 + c] = (_Float16)v;
    else Fs[r * 45 + (c - 10)] = (_Float16)v;
  }
  // zero K-pad cols 146..167
  for (int idx = tid; idx < TB * 22; idx += 256) {
    int r = idx / 22, c = idx - r * 22;
    As[r * AST + 146 + c] = (_Float16)0.f;
  }

  const fx4 zero4 = {0.f, 0.f, 0.f, 0.f};
  fx4 agg[16];
  fx4 acc[16];
  #pragma unroll
  for (int i = 0; i < 16; ++i) agg[i] = zero4;

  for (int p = 0; p < 6; ++p) {
    const int oi = p >> 1;
    const int oj = (1161 >> (2 * p)) & 3; // {1,2,0,2,0,1}
    __syncthreads();
    // ---- build object cols 110..145: [onehot_i(3) feat_i(15) onehot_j(3) feat_j(15)] ----
    for (int idx = tid; idx < TB * 36; idx += 256) {
      int r = idx / 36, c = idx - r * 36;
      _Float16 v;
      if (c < 3)       v = (_Float16)((c == oi) ? 1.f : 0.f);
      else if (c < 18) v = Fs[r * 45 + oi * 15 + (c - 3)];
      else if (c < 21) v = (_Float16)(((c - 18) == oj) ? 1.f : 0.f);
      else             v = Fs[r * 45 + oj * 15 + (c - 21)];
      As[r * AST + 110 + c] = v;
    }
    __syncthreads();

    // ---- GEMM1: h1 = relu(A @ W1 + b1), K=160 (5 k-tiles) ----
    #pragma unroll
    for (int i = 0; i < 16; ++i) acc[i] = zero4;
    for (int kt = 0; kt < 5; ++kt) {
      half8 a[4], b[4];
      #pragma unroll
      for (int m = 0; m < 4; ++m)
        a[m] = *(const half8*)&As[(m * 16 + l16) * AST + kt * 32 + q * 8];
      #pragma unroll
      for (int n = 0; n < 4; ++n)
        b[n] = *(const half8*)&pw1[(kt * 256 + colbase + n * 16 + l16) * 32 + q * 8];
      #pragma unroll
      for (int m = 0; m < 4; ++m)
        #pragma unroll
        for (int n = 0; n < 4; ++n)
          acc[m * 4 + n] = __builtin_amdgcn_mfma_f32_16x16x32_f16(a[m], b[n], acc[m * 4 + n], 0, 0, 0);
    }
    #pragma unroll
    for (int n = 0; n < 4; ++n) {
      float bias = b1[colbase + n * 16 + l16];
      #pragma unroll
      for (int m = 0; m < 4; ++m) {
        fx4 v = acc[m * 4 + n];
        #pragma unroll
        for (int r = 0; r < 4; ++r) {
          float h = v[r] + bias;
          Hs[(m * 16 + q * 4 + r) * HST + colbase + n * 16 + l16] = (_Float16)(h > 0.f ? h : 0.f);
        }
      }
    }
    __syncthreads();

    // ---- GEMM2: agg += relu(h1 @ W2 + b2), K=256 (8 k-tiles) ----
    #pragma unroll
    for (int i = 0; i < 16; ++i) acc[i] = zero4;
    for (int kt = 0; kt < 8; ++kt) {
      half8 a[4], b[4];
      #pragma unroll
      for (int m = 0; m < 4; ++m)
        a[m] = *(const half8*)&Hs[(m * 16 + l16) * HST + kt * 32 + q * 8];
      #pragma unroll
      for (int n = 0; n < 4; ++n)
        b[n] = *(const half8*)&pw2[(kt * 256 + colbase + n * 16 + l16) * 32 + q * 8];
      #pragma unroll
      for (int m = 0; m < 4; ++m)
        #pragma unroll
        for (int n = 0; n < 4; ++n)
          acc[m * 4 + n] = __builtin_amdgcn_mfma_f32_16x16x32_f16(a[m], b[n], acc[m * 4 + n], 0, 0, 0);
    }
    #pragma unroll
    for (int n = 0; n < 4; ++n) {
      float bias = b2[colbase + n * 16 + l16];
      #pragma unroll
      for (int m = 0; m < 4; ++m) {
        #pragma unroll
        for (int r = 0; r < 4; ++r) {
          float h = acc[m * 4 + n][r] + bias;
          if (h > 0.f) agg[m * 4 + n][r] += h;
        }
      }
    }
  }

  __syncthreads();
  // ---- stage agg (>=0 already) into Hs as f16 ----
  #pragma unroll
  for (int n = 0; n < 4; ++n)
    #pragma unroll
    for (int m = 0; m < 4; ++m)
      #pragma unroll
      for (int r = 0; r < 4; ++r)
        Hs[(m * 16 + q * 4 + r) * HST + colbase + n * 16 + l16] = (_Float16)agg[m * 4 + n][r];
  __syncthreads();

  // ---- GEMM3: r = relu(agg @ rho_w1 + rho_b1), K=256 ----
  #pragma unroll
  for (int i = 0; i < 16; ++i) acc[i] = zero4;
  for (int kt = 0; kt < 8; ++kt) {
    half8 a[4], b[4];
    #pragma unroll
    for (int m = 0; m < 4; ++m)
      a[m] = *(const half8*)&Hs[(m * 16 + l16) * HST + kt * 32 + q * 8];
    #pragma unroll
    for (int n = 0; n < 4; ++n)
      b[n] = *(const half8*)&pwr[(kt * 256 + colbase + n * 16 + l16) * 32 + q * 8];
    #pragma unroll
    for (int m = 0; m < 4; ++m)
      #pragma unroll
      for (int n = 0; n < 4; ++n)
        acc[m * 4 + n] = __builtin_amdgcn_mfma_f32_16x16x32_f16(a[m], b[n], acc[m * 4 + n], 0, 0, 0);
  }
  __syncthreads();  // all waves done reading Hs before overwrite
  #pragma unroll
  for (int n = 0; n < 4; ++n) {
    float bias = br[colbase + n * 16 + l16];
    #pragma unroll
    for (int m = 0; m < 4; ++m) {
      #pragma unroll
      for (int r = 0; r < 4; ++r) {
        float h = acc[m * 4 + n][r] + bias;
        Hs[(m * 16 + q * 4 + r) * HST + colbase + n * 16 + l16] = (_Float16)(h > 0.f ? h : 0.f);
      }
    }
  }
  __syncthreads();

  // ---- heads: [mean | log_std] = r @ PWh (N padded to 16), wave w does rows w*16..w*16+15 ----
  fx4 a4 = zero4;
  for (int kt = 0; kt < 8; ++kt) {
    half8 a = *(const half8*)&Hs[(wave * 16 + l16) * HST + kt * 32 + q * 8];
    half8 b = *(const half8*)&pwh[(kt * 16 + l16) * 32 + q * 8];
    a4 = __builtin_amdgcn_mfma_f32_16x16x32_f16(a, b, a4, 0, 0, 0);
  }
  int gr = rowbase + wave * 16 + q * 4;
  if (l16 < 4) {
    float bias = bm[l16];
    #pragma unroll
    for (int r = 0; r < 4; ++r) out[(gr + r) * 4 + l16] = a4[r] + bias;
  } else if (l16 < 8) {
    int c = l16 - 4;
    float bias = bl[c];
    #pragma unroll
    for (int r = 0; r < 4; ++r) {
      float v = a4[r] + bias;
      v = v < -20.f ? -20.f : (v > 2.f ? 2.f : v);
      out[BATCH * 4 + (gr + r) * 4 + c] = v;
    }
  }
}

extern "C" void kernel_launch(void* const* d_in, const int* in_sizes, int n_in,
                              void* d_out, int out_size, void* d_ws, size_t ws_size,
                              hipStream_t stream) {
  const float* obs  = (const float*)d_in[0];
  const float* lemb = (const float*)d_in[1];
  const float* w1   = (const float*)d_in[2];
  const float* b1   = (const float*)d_in[3];
  const float* w2   = (const float*)d_in[4];
  const float* b2   = (const float*)d_in[5];
  const float* wr   = (const float*)d_in[6];
  const float* br   = (const float*)d_in[7];
  const float* wm   = (const float*)d_in[8];
  const float* bm   = (const float*)d_in[9];
  const float* wl   = (const float*)d_in[10];
  const float* bl   = (const float*)d_in[11];
  float* out = (float*)d_out;
  _Float16* ws = (_Float16*)d_ws;

  hipLaunchKernelGGL(prep_weights, dim3((WS_TOTAL + 255) / 256), dim3(256), 0, stream,
                     w1, w2, wr, wm, wl, ws);
  hipLaunchKernelGGL(actor_fused, dim3(BATCH / TB), dim3(256), 0, stream,
                     obs, lemb, (const _Float16*)ws, b1, b2, br, bm, bl, out);
}